// Round 27
// baseline (104.449 us; speedup 1.0000x reference)
//
#include <hip/hip_runtime.h>
#include <math.h>

#define SEQ   2048
#define BATCH 2
#define NH    16
#define DKD   64
#define DM    1024
#define MTOT  (BATCH*SEQ)   // 4096

typedef short bf16x8 __attribute__((ext_vector_type(8)));      // 8 bf16 (4 VGPR)
typedef float f32x4  __attribute__((ext_vector_type(4)));      // MFMA C/D
typedef unsigned short u16x4 __attribute__((ext_vector_type(4)));
typedef unsigned short u16x8 __attribute__((ext_vector_type(8)));

#define MFMA_B16(a,b,c) __builtin_amdgcn_mfma_f32_16x16x32_bf16((a),(b),(c),0,0,0)

__device__ __forceinline__ unsigned short f2bf(float f) {
    union { float f; unsigned int u; } v; v.f = f;
    unsigned int r = v.u + 0x7FFFu + ((v.u >> 16) & 1u);   // RNE
    return (unsigned short)(r >> 16);
}
__device__ __forceinline__ float bf2f(unsigned short h) {
    union { unsigned int u; float f; } v; v.u = ((unsigned int)h) << 16;
    return v.f;
}
__device__ __forceinline__ void gload16(const void* g, void* l) {
    __builtin_amdgcn_global_load_lds(
        (const __attribute__((address_space(1))) unsigned int*)g,
        (__attribute__((address_space(3))) unsigned int*)l, 16, 0, 0);
}

// ---------------- fp32 -> bf16: x + Wq + Wk + Wv + Wo, 32 B/thread ----------------
__global__ __launch_bounds__(256)
void convert_all(const float* __restrict__ x,  const float* __restrict__ Wq,
                 const float* __restrict__ Wk, const float* __restrict__ Wv,
                 const float* __restrict__ Wo,
                 unsigned short* __restrict__ Xb, unsigned short* __restrict__ Wqkvb,
                 unsigned short* __restrict__ Wob)
{
    int i = blockIdx.x * 256 + threadIdx.x;          // 0 .. 1M-1, each 8 floats
    const float* src;
    unsigned short* dst;
    size_t off;
    if (i < (1 << 19)) {                             // x: 4M floats = 512K groups
        src = x; dst = Xb; off = (size_t)i;
    } else {
        int j = i - (1 << 19);
        int wsel = j >> 17;                          // 0..3
        off = (size_t)(j & ((1 << 17) - 1));
        src = (wsel == 0) ? Wq : (wsel == 1) ? Wk : (wsel == 2) ? Wv : Wo;
        dst = (wsel < 3) ? Wqkvb + (size_t)wsel * (1u << 20) : Wob;
    }
    float4 v0 = ((const float4*)src)[off * 2];
    float4 v1 = ((const float4*)src)[off * 2 + 1];
    u16x8 o = { f2bf(v0.x), f2bf(v0.y), f2bf(v0.z), f2bf(v0.w),
                f2bf(v1.x), f2bf(v1.y), f2bf(v1.z), f2bf(v1.w) };
    *(u16x8*)&dst[off * 8] = o;
}

// ---------------- RoPE in place on bf16 Q/K  [bh][s][64], 16 B/thread ----------------
__global__ __launch_bounds__(256)
void rope_bf16(unsigned short* __restrict__ Qb, unsigned short* __restrict__ Kb,
               const int* __restrict__ pos)
{
    int idx = blockIdx.x * 256 + threadIdx.x;    // 0..1M-1 (Q then K), each 8 bf16
    int tsel = idx >> 19;
    int i = idx & ((1 << 19) - 1);
    unsigned short* base = tsel ? Kb : Qb;
    int d8 = i & 7;
    int s  = (i >> 3) & (SEQ - 1);
    float P = (float)pos[s];
    const float NEG_L2 = -0.41524101186092103f;  // -log2(10000)/32

    u16x8 v = *(u16x8*)&base[(size_t)i * 8];
    u16x8 o;
    #pragma unroll
    for (int k = 0; k < 4; ++k) {
        int pi = d8 * 4 + k;
        float ang = P * exp2f((float)pi * NEG_L2);
        float sn, cs;
        sincosf(ang, &sn, &cs);
        float e0 = bf2f(v[2*k]), e1 = bf2f(v[2*k + 1]);
        o[2*k]     = f2bf(e0 * cs - e1 * sn);
        o[2*k + 1] = f2bf(e0 * sn + e1 * cs);
    }
    *(u16x8*)&base[(size_t)i * 8] = o;
}

// ---------------- MFMA GEMM: 16-wave 64x16 sub-tiles, 4-deep pipeline ----------------
// C[M][N] = A[M][K] x B[N][K]^T, bf16 in / f32 acc; 128x128 tile, BK=32, 1024 thr.
// Wave (wm = w>>3, wn = w&7) owns a 64x16 output: 5 ds_read + 4 MFMA per round.
// 4-deep K/V staging (64 KB LDS, still 2 blocks/CU): loads get 3 rounds to land;
// steady-state s_waitcnt vmcnt(2), tail 1 -> 0. Slot (kt+3)&3 was last read at
// round kt-1 -- the barrier at kt protects the overwrite. T2 read-swizzle unchanged.
// MODE 0: N=3072, epilogue scatters Q,K ([bh][s][d]) and V transposed ([bh][d][s])
// MODE 1: N=1024, epilogue writes fp32 row-major C
template<int MODE>
__global__ __launch_bounds__(1024, 8)
void gemm_mfma(const unsigned short* __restrict__ A, const unsigned short* __restrict__ B,
               unsigned short* __restrict__ Qb, unsigned short* __restrict__ Kb,
               unsigned short* __restrict__ VTb, float* __restrict__ Cf)
{
    const int t = threadIdx.x;
    const int w = t >> 6, l = t & 63, lid = l & 15, hi = (l >> 4) * 16;
    const int wm = w >> 3, wn = w & 7;               // 2 x 8 wave grid
    const int m0 = blockIdx.y * 128, n0 = blockIdx.x * 128;

    __shared__ __align__(16) char At[4][8192];       // [128 rows][32 k] bf16, 64 B rows
    __shared__ __align__(16) char Bt[4][8192];

    f32x4 acc[4];
    const f32x4 z4 = {0.f, 0.f, 0.f, 0.f};
    #pragma unroll
    for (int i = 0; i < 4; ++i) acc[i] = z4;

    const char* Ab = (const char*)A;
    const char* Bb = (const char*)B;

    auto stage = [&](int buf, int kt) {              // 1 gload16 per thread
        const int kbyte = kt * 64;
        int o   = (t & 511) * 16;                    // 0..8191
        int row = o >> 6, cb = o & 63;
        int sw  = ((row >> 1) & 3) << 4;             // T2: pre-swizzle global source
        if (t < 512)
            gload16(Ab + (size_t)(m0 + row) * 2048 + kbyte + (cb ^ sw),
                    At[buf] + w * 1024);
        else
            gload16(Bb + (size_t)(n0 + row) * 2048 + kbyte + (cb ^ sw),
                    Bt[buf] + (w - 8) * 1024);
    };

    const int NKT = DM / 32;                         // 32
    stage(0, 0);
    stage(1, 1);
    stage(2, 2);

    for (int kt = 0; kt < NKT; ++kt) {
        const int cur = kt & 3;
        if      (kt <= NKT - 4) asm volatile("s_waitcnt vmcnt(2)" ::: "memory");
        else if (kt == NKT - 3) asm volatile("s_waitcnt vmcnt(2)" ::: "memory");
        else if (kt == NKT - 2) asm volatile("s_waitcnt vmcnt(1)" ::: "memory");
        else                    asm volatile("s_waitcnt vmcnt(0)" ::: "memory");
        __builtin_amdgcn_s_barrier();                // tile kt resident block-wide;
                                                     // buf[(kt+3)&3] free of readers
        if (kt + 3 < NKT) stage((kt + 3) & 3, kt + 3);

        bf16x8 af[4], bfr;
        #pragma unroll
        for (int mf = 0; mf < 4; ++mf) {
            int ar = wm * 64 + mf * 16 + lid;
            af[mf] = *(const bf16x8*)(At[cur] + ar * 64 + (hi ^ (((ar >> 1) & 3) << 4)));
        }
        {
            int br = wn * 16 + lid;
            bfr = *(const bf16x8*)(Bt[cur] + br * 64 + (hi ^ (((br >> 1) & 3) << 4)));
        }
        __builtin_amdgcn_s_setprio(1);
        #pragma unroll
        for (int mf = 0; mf < 4; ++mf)
            acc[mf] = MFMA_B16(af[mf], bfr, acc[mf]);
        __builtin_amdgcn_s_setprio(0);
    }

    if (MODE == 1) {
        #pragma unroll
        for (int mf = 0; mf < 4; ++mf) {
            int ncol = n0 + wn * 16 + lid;
            #pragma unroll
            for (int jj = 0; jj < 4; ++jj) {
                int mrow = m0 + wm * 64 + mf * 16 + (l >> 4) * 4 + jj;
                Cf[(size_t)mrow * DM + ncol] = acc[mf][jj];
            }
        }
    } else {
        const int z = n0 >> 10;                      // 0:Q 1:K 2:V
        const int nbase = n0 & 1023;
        #pragma unroll
        for (int mf = 0; mf < 4; ++mf) {
            int ncol = nbase + wn * 16 + lid;
            int h = ncol >> 6, d = ncol & 63;
            int mbase = m0 + wm * 64 + mf * 16 + (l >> 4) * 4;
            int b = mbase >> 11, s0v = mbase & 2047;
            if (z == 2) {
                u16x4 pk = { f2bf(acc[mf][0]), f2bf(acc[mf][1]),
                             f2bf(acc[mf][2]), f2bf(acc[mf][3]) };
                *(u16x4*)&VTb[((size_t)(b * NH + h) * DKD + d) * SEQ + s0v] = pk;
            } else {
                unsigned short* dst = (z == 0) ? Qb : Kb;
                #pragma unroll
                for (int jj = 0; jj < 4; ++jj)
                    dst[((size_t)(b * NH + h) * SEQ + (s0v + jj)) * DKD + d] =
                        f2bf(acc[mf][jj]);
            }
        }
    }
}

// ---------------- MFMA flash attention: key-split 16-wave blocks (exact R24) -------
// (stays 3-deep: 4-deep would need 80 KB LDS -> 160 KB/CU exactly, the R12 cliff)
__global__ __launch_bounds__(1024, 8)
void flash_mfma(const unsigned short* __restrict__ Qb, const unsigned short* __restrict__ Kb,
                const unsigned short* __restrict__ VTb, unsigned short* __restrict__ AOb)
{
    const int L  = blockIdx.y * 16 + blockIdx.x;     // 0..511
    const int g  = L >> 8, c = L & 255;
    const int j  = c & 15;
    const int bh = (g << 4) | (c >> 4);
    const int b = bh >> 4, h = bh & 15;
    const int qbA = g ? (30 - 2 * j) : (2 * j);
    const int qbB = qbA + 1;

    const int t = threadIdx.x;
    const int w8 = t >> 6, l = t & 63, lid = l & 15, hi = (l >> 4) * 16;
    const int h4 = l >> 4;
    const int tile = w8 >> 3, wq = (w8 >> 1) & 3, kh = w8 & 1;
    const int qbMy = tile ? qbB : qbA;
    const int ntMy = qbMy + 1;
    const int q0My = qbMy * 64;
    const int ntB  = qbB + 1;                        // loop bound (B = A+1), >= 2

    __shared__ __align__(16) char Kt[3][8192];
    __shared__ __align__(16) char Vt[3][8192];
    __shared__ __align__(16) char Pt[2][8192];       // per-tile P

    const char* Kbh = (const char*)(Kb  + (size_t)bh * SEQ * DKD);
    const char* Vbh = (const char*)(VTb + (size_t)bh * SEQ * DKD);
    const char* Qbh = (const char*)(Qb  + (size_t)bh * SEQ * DKD);

    const f32x4 z4 = {0.f, 0.f, 0.f, 0.f};
    const int qrow = wq * 16 + lid;
    const float CLOG = 0.18033688011112042f;     // log2(e)/8
    const float NMC  = -17.312340490667560f;     // -12*log2(e)

    bf16x8 onesv;
    #pragma unroll
    for (int i = 0; i < 8; ++i) onesv[i] = (short)0x3F80;   // bf16 1.0

    bf16x8 qf[2];
    qf[0] = *(const bf16x8*)(Qbh + (size_t)(q0My + qrow) * 128 + 0  + hi);
    qf[1] = *(const bf16x8*)(Qbh + (size_t)(q0My + qrow) * 128 + 64 + hi);

    f32x4 o[4], o5;
    #pragma unroll
    for (int nf = 0; nf < 4; ++nf) o[nf] = z4;
    o5 = z4;

    auto stage = [&](int buf, int kt) {
        if (t < 512) {
            int o_ = t * 16, row = o_ >> 7, cl = o_ & 127, sw = (row & 7) << 4;
            gload16(Kbh + (size_t)(kt * 64 + row) * 128 + (cl ^ sw),
                    Kt[buf] + w8 * 1024);
        } else {
            int o_ = (t - 512) * 16, row = o_ >> 7, cl = o_ & 127, sw = (row & 7) << 4;
            gload16(Vbh + (size_t)row * (SEQ * 2) + kt * 128 + (cl ^ sw),
                    Vt[buf] + (w8 - 8) * 1024);
        }
    };

    stage(0, 0);
    stage(1, 1);

    for (int kt = 0; kt < ntB; ++kt) {
        const int cur = kt % 3;

        if (kt == ntB - 1) asm volatile("s_waitcnt vmcnt(0)" ::: "memory");
        else               asm volatile("s_waitcnt vmcnt(1)" ::: "memory");
        __builtin_amdgcn_s_barrier();
        if (kt + 2 < ntB) stage((kt + 2) % 3, kt + 2);

        if (kt < ntMy) {
            f32x4 sf[2];
            __builtin_amdgcn_s_setprio(1);
            #pragma unroll
            for (int nf = 0; nf < 2; ++nf) {
                f32x4 a = z4;
                #pragma unroll
                for (int ks = 0; ks < 2; ++ks) {
                    int r  = kh * 32 + nf * 16 + lid;
                    int cb = ks * 64 + hi;
                    bf16x8 kfr = *(const bf16x8*)(Kt[cur] + r * 128 + (cb ^ ((r & 7) << 4)));
                    a = MFMA_B16(kfr, qf[ks], a);          // swapped operands
                }
                sf[nf] = a;
            }
            __builtin_amdgcn_s_setprio(0);

            if (kt == qbMy) {
                const int qloc = wq * 16 + lid;
                #pragma unroll
                for (int nf = 0; nf < 2; ++nf) {
                    #pragma unroll
                    for (int jj = 0; jj < 4; ++jj) {
                        int keyloc = kh * 32 + nf * 16 + h4 * 4 + jj;
                        if (keyloc > qloc) sf[nf][jj] = -1e30f;
                    }
                }
            }

            uint2 pk[2];
            #pragma unroll
            for (int nf = 0; nf < 2; ++nf) {
                float p0, p1, p2, p3;
                asm("v_exp_f32 %0, %1" : "=v"(p0) : "v"(fmaf(sf[nf][0], CLOG, NMC)));
                asm("v_exp_f32 %0, %1" : "=v"(p1) : "v"(fmaf(sf[nf][1], CLOG, NMC)));
                asm("v_exp_f32 %0, %1" : "=v"(p2) : "v"(fmaf(sf[nf][2], CLOG, NMC)));
                asm("v_exp_f32 %0, %1" : "=v"(p3) : "v"(fmaf(sf[nf][3], CLOG, NMC)));
                unsigned plo, phi;
                asm("v_cvt_pk_bf16_f32 %0, %1, %2" : "=v"(plo) : "v"(p0), "v"(p1));
                asm("v_cvt_pk_bf16_f32 %0, %1, %2" : "=v"(phi) : "v"(p2), "v"(p3));
                pk[nf].x = plo; pk[nf].y = phi;
            }

            {
                const int swz  = (lid & 7) << 4;
                char* base = Pt[tile] + qrow * 128;
                #pragma unroll
                for (int nf = 0; nf < 2; ++nf)
                    *(uint2*)(base + ((kh * 64 + nf * 32 + 8 * h4) ^ swz)) = pk[nf];
            }

            {
                int cb = kh * 64 + hi;
                bf16x8 pa = *(const bf16x8*)(Pt[tile] + qrow * 128 + (cb ^ ((qrow & 7) << 4)));
                __builtin_amdgcn_s_setprio(1);
                #pragma unroll
                for (int nf = 0; nf < 4; ++nf) {
                    int dr = nf * 16 + lid;
                    bf16x8 vb = *(const bf16x8*)(Vt[cur] + dr * 128 + (cb ^ ((dr & 7) << 4)));
                    o[nf] = MFMA_B16(pa, vb, o[nf]);
                }
                o5 = MFMA_B16(pa, onesv, o5);
                __builtin_amdgcn_s_setprio(0);
            }
        }
    }

    // ---- epilogue: merge key-half partials (waves w8, w8^1), normalize, store ----
    __syncthreads();                                 // K/V LDS now dead -> scratch
    const int ww = w8 >> 1;                          // pair index 0..7
    char* scr = (ww < 4) ? ((char*)Kt + ww * 5120)
                         : ((char*)Vt + (ww - 4) * 5120);
    if (kh == 1) {                                   // writer: 5 x float4 per lane
        #pragma unroll
        for (int nf = 0; nf < 4; ++nf)
            *(f32x4*)(scr + l * 80 + nf * 16) = o[nf];
        *(f32x4*)(scr + l * 80 + 64) = o5;
    }
    __syncthreads();
    if (kh == 0) {
        #pragma unroll
        for (int nf = 0; nf < 4; ++nf) {
            f32x4 po = *(const f32x4*)(scr + l * 80 + nf * 16);
            o[nf] += po;
        }
        f32x4 po5 = *(const f32x4*)(scr + l * 80 + 64);
        o5 += po5;

        float inv[4];
        #pragma unroll
        for (int jj = 0; jj < 4; ++jj) inv[jj] = 1.0f / o5[jj];
        #pragma unroll
        for (int nf = 0; nf < 4; ++nf)
            #pragma unroll
            for (int jj = 0; jj < 4; ++jj) {
                int srow = q0My + wq * 16 + h4 * 4 + jj;
                int col  = h * 64 + nf * 16 + lid;
                AOb[((size_t)b * SEQ + srow) * DM + col] = f2bf(o[nf][jj] * inv[jj]);
            }
    }
}

// ---------------- launch ----------------
extern "C" void kernel_launch(void* const* d_in, const int* in_sizes, int n_in,
                              void* d_out, int out_size, void* d_ws, size_t ws_size,
                              hipStream_t stream)
{
    const float* x   = (const float*)d_in[0];
    const int*   pos = (const int*)  d_in[1];
    const float* Wq  = (const float*)d_in[2];
    const float* Wk  = (const float*)d_in[3];
    const float* Wv  = (const float*)d_in[4];
    const float* Wo  = (const float*)d_in[5];
    float* out = (float*)d_out;

    const size_t M1 = 1u << 20;                 // 1M elements
    unsigned short* ws  = (unsigned short*)d_ws;
    unsigned short* Xb    = ws;                 // 4M
    unsigned short* Wqkvb = ws + 4 * M1;        // 3M (Wq|Wk|Wv rows)
    unsigned short* Wob   = ws + 7 * M1;        // 1M
    unsigned short* Qbf   = ws + 8 * M1;        // 4M  [bh][s][64]
    unsigned short* Kbf   = ws + 12 * M1;       // 4M  [bh][s][64]
    unsigned short* VTb   = ws + 16 * M1;       // 4M  [bh][64][s]
    unsigned short* AOb   = ws + 20 * M1;       // 4M  [b*s][1024]

    convert_all<<<4096, 256, 0, stream>>>(x, Wq, Wk, Wv, Wo, Xb, Wqkvb, Wob);

    // QKV projection (epilogue scatters Q,K row-major; V transposed)
    gemm_mfma<0><<<dim3(24, 32), 1024, 0, stream>>>(Xb, Wqkvb, Qbf, Kbf, VTb, nullptr);

    // RoPE in place on bf16 Q/K
    rope_bf16<<<4096, 256, 0, stream>>>(Qbf, Kbf, pos);

    // flash attention (16-wave key-split blocks, counted-vmcnt 3-deep pipeline)
    flash_mfma<<<dim3(16, 32), 1024, 0, stream>>>(Qbf, Kbf, VTb, AOb);

    // output projection
    gemm_mfma<1><<<dim3(8, 32), 1024, 0, stream>>>(AOb, Wob, nullptr, nullptr, nullptr, out);
}

// Round 28
// 101.595 us; speedup vs baseline: 1.0281x; 1.0281x over previous
//
#include <hip/hip_runtime.h>
#include <math.h>

#define SEQ   2048
#define BATCH 2
#define NH    16
#define DKD   64
#define DM    1024
#define MTOT  (BATCH*SEQ)   // 4096

typedef short bf16x8 __attribute__((ext_vector_type(8)));      // 8 bf16 (4 VGPR)
typedef float f32x4  __attribute__((ext_vector_type(4)));      // MFMA C/D
typedef unsigned short u16x4 __attribute__((ext_vector_type(4)));
typedef unsigned short u16x8 __attribute__((ext_vector_type(8)));

#define MFMA_B16(a,b,c) __builtin_amdgcn_mfma_f32_16x16x32_bf16((a),(b),(c),0,0,0)

__device__ __forceinline__ unsigned short f2bf(float f) {
    union { float f; unsigned int u; } v; v.f = f;
    unsigned int r = v.u + 0x7FFFu + ((v.u >> 16) & 1u);   // RNE
    return (unsigned short)(r >> 16);
}
__device__ __forceinline__ float bf2f(unsigned short h) {
    union { unsigned int u; float f; } v; v.u = ((unsigned int)h) << 16;
    return v.f;
}
__device__ __forceinline__ void gload16(const void* g, void* l) {
    __builtin_amdgcn_global_load_lds(
        (const __attribute__((address_space(1))) unsigned int*)g,
        (__attribute__((address_space(3))) unsigned int*)l, 16, 0, 0);
}

// ---------------- fp32 -> bf16: x + Wq + Wk + Wv + Wo, 32 B/thread ----------------
__global__ __launch_bounds__(256)
void convert_all(const float* __restrict__ x,  const float* __restrict__ Wq,
                 const float* __restrict__ Wk, const float* __restrict__ Wv,
                 const float* __restrict__ Wo,
                 unsigned short* __restrict__ Xb, unsigned short* __restrict__ Wqkvb,
                 unsigned short* __restrict__ Wob)
{
    int i = blockIdx.x * 256 + threadIdx.x;          // 0 .. 1M-1, each 8 floats
    const float* src;
    unsigned short* dst;
    size_t off;
    if (i < (1 << 19)) {                             // x: 4M floats = 512K groups
        src = x; dst = Xb; off = (size_t)i;
    } else {
        int j = i - (1 << 19);
        int wsel = j >> 17;                          // 0..3
        off = (size_t)(j & ((1 << 17) - 1));
        src = (wsel == 0) ? Wq : (wsel == 1) ? Wk : (wsel == 2) ? Wv : Wo;
        dst = (wsel < 3) ? Wqkvb + (size_t)wsel * (1u << 20) : Wob;
    }
    float4 v0 = ((const float4*)src)[off * 2];
    float4 v1 = ((const float4*)src)[off * 2 + 1];
    u16x8 o = { f2bf(v0.x), f2bf(v0.y), f2bf(v0.z), f2bf(v0.w),
                f2bf(v1.x), f2bf(v1.y), f2bf(v1.z), f2bf(v1.w) };
    *(u16x8*)&dst[off * 8] = o;
}

// ---------------- RoPE in place on bf16 Q/K  [bh][s][64], 16 B/thread ----------------
__global__ __launch_bounds__(256)
void rope_bf16(unsigned short* __restrict__ Qb, unsigned short* __restrict__ Kb,
               const int* __restrict__ pos)
{
    int idx = blockIdx.x * 256 + threadIdx.x;    // 0..1M-1 (Q then K), each 8 bf16
    int tsel = idx >> 19;
    int i = idx & ((1 << 19) - 1);
    unsigned short* base = tsel ? Kb : Qb;
    int d8 = i & 7;
    int s  = (i >> 3) & (SEQ - 1);
    float P = (float)pos[s];
    const float NEG_L2 = -0.41524101186092103f;  // -log2(10000)/32

    u16x8 v = *(u16x8*)&base[(size_t)i * 8];
    u16x8 o;
    #pragma unroll
    for (int k = 0; k < 4; ++k) {
        int pi = d8 * 4 + k;
        float ang = P * exp2f((float)pi * NEG_L2);
        float sn, cs;
        sincosf(ang, &sn, &cs);
        float e0 = bf2f(v[2*k]), e1 = bf2f(v[2*k + 1]);
        o[2*k]     = f2bf(e0 * cs - e1 * sn);
        o[2*k + 1] = f2bf(e0 * sn + e1 * cs);
    }
    *(u16x8*)&base[(size_t)i * 8] = o;
}

// ---------------- MFMA GEMM: 16-wave 64x16 sub-tiles, 3-deep (exact R26 best) ------
// C[M][N] = A[M][K] x B[N][K]^T, bf16 in / f32 acc; 128x128 tile, BK=32, 1024 thr.
// Wave (wm = w>>3, wn = w&7) owns a 64x16 output: 5 ds_read + 4 MFMA per round.
// Staging: waves 0-7 stage A, 8-15 stage B (1 gload16/thread, wave-uniform);
// 3-deep counted vmcnt(1). T2 read-swizzle (0 conflicts). 4-deep regressed (R27);
// BK=64 regressed (R22) -- this is the measured optimum of the structure family.
// MODE 0: N=3072, epilogue scatters Q,K ([bh][s][d]) and V transposed ([bh][d][s])
// MODE 1: N=1024, epilogue writes fp32 row-major C
template<int MODE>
__global__ __launch_bounds__(1024, 8)
void gemm_mfma(const unsigned short* __restrict__ A, const unsigned short* __restrict__ B,
               unsigned short* __restrict__ Qb, unsigned short* __restrict__ Kb,
               unsigned short* __restrict__ VTb, float* __restrict__ Cf)
{
    const int t = threadIdx.x;
    const int w = t >> 6, l = t & 63, lid = l & 15, hi = (l >> 4) * 16;
    const int wm = w >> 3, wn = w & 7;               // 2 x 8 wave grid
    const int m0 = blockIdx.y * 128, n0 = blockIdx.x * 128;

    __shared__ __align__(16) char At[3][8192];       // [128 rows][32 k] bf16, 64 B rows
    __shared__ __align__(16) char Bt[3][8192];

    f32x4 acc[4];
    const f32x4 z4 = {0.f, 0.f, 0.f, 0.f};
    #pragma unroll
    for (int i = 0; i < 4; ++i) acc[i] = z4;

    const char* Ab = (const char*)A;
    const char* Bb = (const char*)B;

    auto stage = [&](int buf, int kt) {              // 1 gload16 per thread
        const int kbyte = kt * 64;
        int o   = (t & 511) * 16;                    // 0..8191
        int row = o >> 6, cb = o & 63;
        int sw  = ((row >> 1) & 3) << 4;             // T2: pre-swizzle global source
        if (t < 512)
            gload16(Ab + (size_t)(m0 + row) * 2048 + kbyte + (cb ^ sw),
                    At[buf] + w * 1024);
        else
            gload16(Bb + (size_t)(n0 + row) * 2048 + kbyte + (cb ^ sw),
                    Bt[buf] + (w - 8) * 1024);
    };

    const int NKT = DM / 32;                         // 32
    stage(0, 0);
    stage(1, 1);

    for (int kt = 0; kt < NKT; ++kt) {
        const int cur = kt % 3;
        if (kt == NKT - 1) asm volatile("s_waitcnt vmcnt(0)" ::: "memory");
        else               asm volatile("s_waitcnt vmcnt(1)" ::: "memory");
        __builtin_amdgcn_s_barrier();                // tile kt resident block-wide;
                                                     // buf[(kt+2)%3] free of readers
        if (kt + 2 < NKT) stage((kt + 2) % 3, kt + 2);

        bf16x8 af[4], bfr;
        #pragma unroll
        for (int mf = 0; mf < 4; ++mf) {
            int ar = wm * 64 + mf * 16 + lid;
            af[mf] = *(const bf16x8*)(At[cur] + ar * 64 + (hi ^ (((ar >> 1) & 3) << 4)));
        }
        {
            int br = wn * 16 + lid;
            bfr = *(const bf16x8*)(Bt[cur] + br * 64 + (hi ^ (((br >> 1) & 3) << 4)));
        }
        __builtin_amdgcn_s_setprio(1);
        #pragma unroll
        for (int mf = 0; mf < 4; ++mf)
            acc[mf] = MFMA_B16(af[mf], bfr, acc[mf]);
        __builtin_amdgcn_s_setprio(0);
    }

    if (MODE == 1) {
        #pragma unroll
        for (int mf = 0; mf < 4; ++mf) {
            int ncol = n0 + wn * 16 + lid;
            #pragma unroll
            for (int jj = 0; jj < 4; ++jj) {
                int mrow = m0 + wm * 64 + mf * 16 + (l >> 4) * 4 + jj;
                Cf[(size_t)mrow * DM + ncol] = acc[mf][jj];
            }
        }
    } else {
        const int z = n0 >> 10;                      // 0:Q 1:K 2:V
        const int nbase = n0 & 1023;
        #pragma unroll
        for (int mf = 0; mf < 4; ++mf) {
            int ncol = nbase + wn * 16 + lid;
            int h = ncol >> 6, d = ncol & 63;
            int mbase = m0 + wm * 64 + mf * 16 + (l >> 4) * 4;
            int b = mbase >> 11, s0v = mbase & 2047;
            if (z == 2) {
                u16x4 pk = { f2bf(acc[mf][0]), f2bf(acc[mf][1]),
                             f2bf(acc[mf][2]), f2bf(acc[mf][3]) };
                *(u16x4*)&VTb[((size_t)(b * NH + h) * DKD + d) * SEQ + s0v] = pk;
            } else {
                unsigned short* dst = (z == 0) ? Qb : Kb;
                #pragma unroll
                for (int jj = 0; jj < 4; ++jj)
                    dst[((size_t)(b * NH + h) * SEQ + (s0v + jj)) * DKD + d] =
                        f2bf(acc[mf][jj]);
            }
        }
    }
}

// ---------------- MFMA flash attention: key-split 16-wave blocks (exact R24) -------
__global__ __launch_bounds__(1024, 8)
void flash_mfma(const unsigned short* __restrict__ Qb, const unsigned short* __restrict__ Kb,
                const unsigned short* __restrict__ VTb, unsigned short* __restrict__ AOb)
{
    const int L  = blockIdx.y * 16 + blockIdx.x;     // 0..511
    const int g  = L >> 8, c = L & 255;
    const int j  = c & 15;
    const int bh = (g << 4) | (c >> 4);
    const int b = bh >> 4, h = bh & 15;
    const int qbA = g ? (30 - 2 * j) : (2 * j);
    const int qbB = qbA + 1;

    const int t = threadIdx.x;
    const int w8 = t >> 6, l = t & 63, lid = l & 15, hi = (l >> 4) * 16;
    const int h4 = l >> 4;
    const int tile = w8 >> 3, wq = (w8 >> 1) & 3, kh = w8 & 1;
    const int qbMy = tile ? qbB : qbA;
    const int ntMy = qbMy + 1;
    const int q0My = qbMy * 64;
    const int ntB  = qbB + 1;                        // loop bound (B = A+1), >= 2

    __shared__ __align__(16) char Kt[3][8192];
    __shared__ __align__(16) char Vt[3][8192];
    __shared__ __align__(16) char Pt[2][8192];       // per-tile P

    const char* Kbh = (const char*)(Kb  + (size_t)bh * SEQ * DKD);
    const char* Vbh = (const char*)(VTb + (size_t)bh * SEQ * DKD);
    const char* Qbh = (const char*)(Qb  + (size_t)bh * SEQ * DKD);

    const f32x4 z4 = {0.f, 0.f, 0.f, 0.f};
    const int qrow = wq * 16 + lid;
    const float CLOG = 0.18033688011112042f;     // log2(e)/8
    const float NMC  = -17.312340490667560f;     // -12*log2(e)

    bf16x8 onesv;
    #pragma unroll
    for (int i = 0; i < 8; ++i) onesv[i] = (short)0x3F80;   // bf16 1.0

    bf16x8 qf[2];
    qf[0] = *(const bf16x8*)(Qbh + (size_t)(q0My + qrow) * 128 + 0  + hi);
    qf[1] = *(const bf16x8*)(Qbh + (size_t)(q0My + qrow) * 128 + 64 + hi);

    f32x4 o[4], o5;
    #pragma unroll
    for (int nf = 0; nf < 4; ++nf) o[nf] = z4;
    o5 = z4;

    auto stage = [&](int buf, int kt) {
        if (t < 512) {
            int o_ = t * 16, row = o_ >> 7, cl = o_ & 127, sw = (row & 7) << 4;
            gload16(Kbh + (size_t)(kt * 64 + row) * 128 + (cl ^ sw),
                    Kt[buf] + w8 * 1024);
        } else {
            int o_ = (t - 512) * 16, row = o_ >> 7, cl = o_ & 127, sw = (row & 7) << 4;
            gload16(Vbh + (size_t)row * (SEQ * 2) + kt * 128 + (cl ^ sw),
                    Vt[buf] + (w8 - 8) * 1024);
        }
    };

    stage(0, 0);
    stage(1, 1);

    for (int kt = 0; kt < ntB; ++kt) {
        const int cur = kt % 3;

        if (kt == ntB - 1) asm volatile("s_waitcnt vmcnt(0)" ::: "memory");
        else               asm volatile("s_waitcnt vmcnt(1)" ::: "memory");
        __builtin_amdgcn_s_barrier();
        if (kt + 2 < ntB) stage((kt + 2) % 3, kt + 2);

        if (kt < ntMy) {
            f32x4 sf[2];
            __builtin_amdgcn_s_setprio(1);
            #pragma unroll
            for (int nf = 0; nf < 2; ++nf) {
                f32x4 a = z4;
                #pragma unroll
                for (int ks = 0; ks < 2; ++ks) {
                    int r  = kh * 32 + nf * 16 + lid;
                    int cb = ks * 64 + hi;
                    bf16x8 kfr = *(const bf16x8*)(Kt[cur] + r * 128 + (cb ^ ((r & 7) << 4)));
                    a = MFMA_B16(kfr, qf[ks], a);          // swapped operands
                }
                sf[nf] = a;
            }
            __builtin_amdgcn_s_setprio(0);

            if (kt == qbMy) {
                const int qloc = wq * 16 + lid;
                #pragma unroll
                for (int nf = 0; nf < 2; ++nf) {
                    #pragma unroll
                    for (int jj = 0; jj < 4; ++jj) {
                        int keyloc = kh * 32 + nf * 16 + h4 * 4 + jj;
                        if (keyloc > qloc) sf[nf][jj] = -1e30f;
                    }
                }
            }

            uint2 pk[2];
            #pragma unroll
            for (int nf = 0; nf < 2; ++nf) {
                float p0, p1, p2, p3;
                asm("v_exp_f32 %0, %1" : "=v"(p0) : "v"(fmaf(sf[nf][0], CLOG, NMC)));
                asm("v_exp_f32 %0, %1" : "=v"(p1) : "v"(fmaf(sf[nf][1], CLOG, NMC)));
                asm("v_exp_f32 %0, %1" : "=v"(p2) : "v"(fmaf(sf[nf][2], CLOG, NMC)));
                asm("v_exp_f32 %0, %1" : "=v"(p3) : "v"(fmaf(sf[nf][3], CLOG, NMC)));
                unsigned plo, phi;
                asm("v_cvt_pk_bf16_f32 %0, %1, %2" : "=v"(plo) : "v"(p0), "v"(p1));
                asm("v_cvt_pk_bf16_f32 %0, %1, %2" : "=v"(phi) : "v"(p2), "v"(p3));
                pk[nf].x = plo; pk[nf].y = phi;
            }

            {
                const int swz  = (lid & 7) << 4;
                char* base = Pt[tile] + qrow * 128;
                #pragma unroll
                for (int nf = 0; nf < 2; ++nf)
                    *(uint2*)(base + ((kh * 64 + nf * 32 + 8 * h4) ^ swz)) = pk[nf];
            }

            {
                int cb = kh * 64 + hi;
                bf16x8 pa = *(const bf16x8*)(Pt[tile] + qrow * 128 + (cb ^ ((qrow & 7) << 4)));
                __builtin_amdgcn_s_setprio(1);
                #pragma unroll
                for (int nf = 0; nf < 4; ++nf) {
                    int dr = nf * 16 + lid;
                    bf16x8 vb = *(const bf16x8*)(Vt[cur] + dr * 128 + (cb ^ ((dr & 7) << 4)));
                    o[nf] = MFMA_B16(pa, vb, o[nf]);
                }
                o5 = MFMA_B16(pa, onesv, o5);
                __builtin_amdgcn_s_setprio(0);
            }
        }
    }

    // ---- epilogue: merge key-half partials (waves w8, w8^1), normalize, store ----
    __syncthreads();                                 // K/V LDS now dead -> scratch
    const int ww = w8 >> 1;                          // pair index 0..7
    char* scr = (ww < 4) ? ((char*)Kt + ww * 5120)
                         : ((char*)Vt + (ww - 4) * 5120);
    if (kh == 1) {                                   // writer: 5 x float4 per lane
        #pragma unroll
        for (int nf = 0; nf < 4; ++nf)
            *(f32x4*)(scr + l * 80 + nf * 16) = o[nf];
        *(f32x4*)(scr + l * 80 + 64) = o5;
    }
    __syncthreads();
    if (kh == 0) {
        #pragma unroll
        for (int nf = 0; nf < 4; ++nf) {
            f32x4 po = *(const f32x4*)(scr + l * 80 + nf * 16);
            o[nf] += po;
        }
        f32x4 po5 = *(const f32x4*)(scr + l * 80 + 64);
        o5 += po5;

        float inv[4];
        #pragma unroll
        for (int jj = 0; jj < 4; ++jj) inv[jj] = 1.0f / o5[jj];
        #pragma unroll
        for (int nf = 0; nf < 4; ++nf)
            #pragma unroll
            for (int jj = 0; jj < 4; ++jj) {
                int srow = q0My + wq * 16 + h4 * 4 + jj;
                int col  = h * 64 + nf * 16 + lid;
                AOb[((size_t)b * SEQ + srow) * DM + col] = f2bf(o[nf][jj] * inv[jj]);
            }
    }
}

// ---------------- launch ----------------
extern "C" void kernel_launch(void* const* d_in, const int* in_sizes, int n_in,
                              void* d_out, int out_size, void* d_ws, size_t ws_size,
                              hipStream_t stream)
{
    const float* x   = (const float*)d_in[0];
    const int*   pos = (const int*)  d_in[1];
    const float* Wq  = (const float*)d_in[2];
    const float* Wk  = (const float*)d_in[3];
    const float* Wv  = (const float*)d_in[4];
    const float* Wo  = (const float*)d_in[5];
    float* out = (float*)d_out;

    const size_t M1 = 1u << 20;                 // 1M elements
    unsigned short* ws  = (unsigned short*)d_ws;
    unsigned short* Xb    = ws;                 // 4M
    unsigned short* Wqkvb = ws + 4 * M1;        // 3M (Wq|Wk|Wv rows)
    unsigned short* Wob   = ws + 7 * M1;        // 1M
    unsigned short* Qbf   = ws + 8 * M1;        // 4M  [bh][s][64]
    unsigned short* Kbf   = ws + 12 * M1;       // 4M  [bh][s][64]
    unsigned short* VTb   = ws + 16 * M1;       // 4M  [bh][64][s]
    unsigned short* AOb   = ws + 20 * M1;       // 4M  [b*s][1024]

    convert_all<<<4096, 256, 0, stream>>>(x, Wq, Wk, Wv, Wo, Xb, Wqkvb, Wob);

    // QKV projection (epilogue scatters Q,K row-major; V transposed)
    gemm_mfma<0><<<dim3(24, 32), 1024, 0, stream>>>(Xb, Wqkvb, Qbf, Kbf, VTb, nullptr);

    // RoPE in place on bf16 Q/K
    rope_bf16<<<4096, 256, 0, stream>>>(Qbf, Kbf, pos);

    // flash attention (16-wave key-split blocks, counted-vmcnt 3-deep pipeline)
    flash_mfma<<<dim3(16, 32), 1024, 0, stream>>>(Qbf, Kbf, VTb, AOb);

    // output projection
    gemm_mfma<1><<<dim3(8, 32), 1024, 0, stream>>>(AOb, Wob, nullptr, nullptr, nullptr, out);
}